// Round 2
// baseline (559.507 us; speedup 1.0000x reference)
//
#include <hip/hip_runtime.h>
#include <hip/hip_cooperative_groups.h>

namespace cg = cooperative_groups;

// InterpretableMultiHeadAttention  B=1, S=384, D=512, H=8, DK=64
// fp32 in/out (R1/R3 findings from prior session).
//
// Factored algebra (exact):
//   scores_h = 0.125*(q_h (Wq_h Wk_h^T) k_h^T + q_h.uq + k_h.uk + c)
//   hvo_h    = v_h (Wv_s Wo / 8) + pb
//   out[s,t,:] = sum_h attn[h,s,t]*hvo[h,t,:] + bo
//
// R4: 12 dispatches -> 5 (-132 us => ~19 us/dispatch overhead measured).
// R5 (this round): 5 dispatches -> 1 cooperative mega-kernel with grid.sync()
// between phases. Softmax rewritten wave-per-row (shfl_xor, no LDS tree).
// Work->block mapping spread evenly over the grid so small phases don't
// pack onto few CUs. Epilogue keeps float4 + nontemporal stores.

#define SS_ 384
#define DD_ 512
#define HH_ 8
#define DKK_ 64
#define SSZ_ (SS_ * SS_)

typedef float f32x4 __attribute__((ext_vector_type(4)));

// ---- generic 64x64-tile fp32 GEMM, K multiple of 64, 256 threads ----------
// C[m0+m, n0+n] = scale*(sum_k A[m,k]*B[k,n] + rvec[m] + zvec[n]) + bias[n]
// NT=true: B accessed as B[n, k] (row-major [N,K]).
template <bool NT>
__device__ __forceinline__ void tile64(
    float (* __restrict__ As)[65], float (* __restrict__ Bs)[65],
    const float* __restrict__ A, int lda,
    const float* __restrict__ B, int ldb,
    const float* __restrict__ bias,
    const float* __restrict__ rvec,
    const float* __restrict__ zvec,
    float scale,
    float* __restrict__ C, int ldc, int K, int m0, int n0)
{
    const int tid = threadIdx.x;
    const int lr = tid >> 2;           // 0..63
    const int lc = (tid & 3) << 4;     // 0,16,32,48
    const int ty = tid >> 4, tx = tid & 15;
    float acc[4][4] = {};

    for (int k0 = 0; k0 < K; k0 += 64) {
        const float* Ap = A + (size_t)(m0 + lr) * lda + (k0 + lc);
#pragma unroll
        for (int u = 0; u < 16; u += 4) {
            float4 t4 = *(const float4*)(Ap + u);
            As[lr][lc + u + 0] = t4.x; As[lr][lc + u + 1] = t4.y;
            As[lr][lc + u + 2] = t4.z; As[lr][lc + u + 3] = t4.w;
        }
        if (!NT) {
            const float* Bp = B + (size_t)(k0 + lr) * ldb + (n0 + lc);
#pragma unroll
            for (int u = 0; u < 16; u += 4) {
                float4 t4 = *(const float4*)(Bp + u);
                Bs[lr][lc + u + 0] = t4.x; Bs[lr][lc + u + 1] = t4.y;
                Bs[lr][lc + u + 2] = t4.z; Bs[lr][lc + u + 3] = t4.w;
            }
        } else {
            const float* Bp = B + (size_t)(n0 + lr) * ldb + (k0 + lc);
#pragma unroll
            for (int u = 0; u < 16; ++u) Bs[lc + u][lr] = Bp[u];
        }
        __syncthreads();
#pragma unroll 16
        for (int kk = 0; kk < 64; ++kk) {
            float a[4], b[4];
#pragma unroll
            for (int i = 0; i < 4; ++i) a[i] = As[(ty << 2) + i][kk];
#pragma unroll
            for (int j = 0; j < 4; ++j) b[j] = Bs[kk][(tx << 2) + j];
#pragma unroll
            for (int i = 0; i < 4; ++i)
#pragma unroll
                for (int j = 0; j < 4; ++j)
                    acc[i][j] = fmaf(a[i], b[j], acc[i][j]);
        }
        __syncthreads();
    }
#pragma unroll
    for (int i = 0; i < 4; ++i) {
        const int m = m0 + (ty << 2) + i;
#pragma unroll
        for (int j = 0; j < 4; ++j) {
            const int n = n0 + (tx << 2) + j;
            float val = acc[i][j];
            if (rvec) val += rvec[m];
            if (zvec) val += zvec[n];
            val *= scale;
            if (bias) val += bias[n];
            C[(size_t)m * ldc + n] = val;
        }
    }
}

// evenly-spread contiguous partition of W items over nb blocks (W <= nb or not)
__device__ __forceinline__ void part(int W, int nb, int bid, int& lo, int& hi)
{
    lo = (int)(((long long)bid * W) / nb);
    hi = (int)(((long long)(bid + 1) * W) / nb);
}

__global__ __launch_bounds__(256) void mega_kernel(
    const float* __restrict__ x,
    const float* __restrict__ Wq, const float* __restrict__ bq,
    const float* __restrict__ Wk, const float* __restrict__ bk,
    const float* __restrict__ Wv, const float* __restrict__ bv,
    const float* __restrict__ Wq_h, const float* __restrict__ bq_h,
    const float* __restrict__ Wk_h, const float* __restrict__ bk_h,
    const float* __restrict__ Wv_s, const float* __restrict__ bv_s,
    const float* __restrict__ Wo, const float* __restrict__ bo,
    float* __restrict__ q, float* __restrict__ k, float* __restrict__ v,
    float* __restrict__ M, float* __restrict__ uq, float* __restrict__ uk,
    float* __restrict__ cc, float* __restrict__ N, float* __restrict__ r,
    float* __restrict__ z, float* __restrict__ P, float* __restrict__ pb,
    float* __restrict__ attn, float* __restrict__ hvo,
    float* __restrict__ out0, float* __restrict__ out1)
{
    __shared__ float As[64][65];
    __shared__ float Bs[64][65];
    cg::grid_group grid = cg::this_grid();
    const int bid = threadIdx.y == 0 ? blockIdx.x : 0; // (ty unused; keep 1D)
    const int tid = threadIdx.x;
    const int nb = gridDim.x;
    int lo, hi;

    // ================= P1: all input-only work (167 items) =================
    // 0..7 pcM | 8..12 pcUV | 13..20 pcP | 21..22 pcPb | 23..166 qkv
    part(167, nb, bid, lo, hi);
    for (int it = lo; it < hi; ++it) {
        if (it < 8) {
            const int h = it;
            tile64<true>(As, Bs,
                         Wq_h + (size_t)h * DKK_ * DD_, DD_,
                         Wk_h + (size_t)h * DKK_ * DD_, DD_,
                         nullptr, nullptr, nullptr, 1.0f,
                         M + (size_t)h * DKK_ * DKK_, DKK_, DD_, 0, 0);
        } else if (it < 13) {
            const int id = (it - 8) * 256 + tid;
            if (id < 512) {
                const int h = id >> 6, i = id & 63;
                float s = 0.f;
                for (int d = 0; d < DD_; ++d)
                    s = fmaf(Wq_h[(size_t)(h * DKK_ + i) * DD_ + d], bk_h[h * DD_ + d], s);
                uq[id] = s;
            } else if (id < 1024) {
                const int t2 = id - 512, h = t2 >> 6, j = t2 & 63;
                float s = 0.f;
                for (int d = 0; d < DD_; ++d)
                    s = fmaf(Wk_h[(size_t)(h * DKK_ + j) * DD_ + d], bq_h[h * DD_ + d], s);
                uk[t2] = s;
            } else if (id < 1032) {
                const int h = id - 1024;
                float s = 0.f;
                for (int d = 0; d < DD_; ++d)
                    s = fmaf(bq_h[h * DD_ + d], bk_h[h * DD_ + d], s);
                cc[h] = s;
            }
        } else if (it < 21) {
            tile64<false>(As, Bs, Wv_s, DD_, Wo, DD_, nullptr, nullptr, nullptr,
                          0.125f, P, DD_, DD_, 0, (it - 13) * 64);
        } else if (it < 23) {
            const int e = (it - 21) * 256 + tid;
            if (e < DD_) {
                float s = 0.f;
                for (int d = 0; d < DD_; ++d)
                    s = fmaf(bv_s[d], Wo[(size_t)d * DD_ + e], s);
                pb[e] = 0.125f * s;
            }
        } else {
            const int id = it - 23;                // 0..143
            const int zi = id / 48;
            const int rem = id % 48;
            const int my = rem >> 3, nx = rem & 7;
            const float *W, *bias; float* C;
            if (zi == 0)      { W = Wq; bias = bq; C = q; }
            else if (zi == 1) { W = Wk; bias = bk; C = k; }
            else              { W = Wv; bias = bv; C = v; }
            tile64<false>(As, Bs, x, DD_, W, DD_, bias, nullptr, nullptr, 1.0f,
                          C, DD_, DD_, my * 64, nx * 64);
        }
    }
    grid.sync();

    // ================= P2: stage2 (456 items) ==============================
    // 0..47 nK | 48..71 rz | 72..455 hvo
    part(456, nb, bid, lo, hi);
    for (int it = lo; it < hi; ++it) {
        if (it < 48) {
            const int h = it / 6, mx = it % 6;
            tile64<false>(As, Bs, q + h * DKK_, DD_,
                          M + (size_t)h * DKK_ * DKK_, DKK_,
                          nullptr, nullptr, nullptr, 1.0f,
                          N + (size_t)h * SS_ * DKK_, DKK_, DKK_, mx * 64, 0);
        } else if (it < 72) {
            const int id = (it - 48) * 256 + tid;
            if (id < HH_ * SS_) {
                const int h = id / SS_, s = id % SS_;
                float acc = cc[h];
                for (int i = 0; i < DKK_; ++i)
                    acc = fmaf(q[(size_t)s * DD_ + h * DKK_ + i], uq[h * DKK_ + i], acc);
                r[id] = acc;
            } else if (id < 2 * HH_ * SS_) {
                const int t2 = id - HH_ * SS_;
                const int h = t2 / SS_, t = t2 % SS_;
                float acc = 0.f;
                for (int j = 0; j < DKK_; ++j)
                    acc = fmaf(k[(size_t)t * DD_ + h * DKK_ + j], uk[h * DKK_ + j], acc);
                z[t2] = acc;
            }
        } else {
            const int id = it - 72;                // 0..383
            const int nx = id & 7;
            const int my = (id >> 3) % 6;
            const int h = id / 48;
            tile64<false>(As, Bs, v + h * DKK_, DD_, P, DD_, pb, nullptr, nullptr,
                          1.0f, hvo + (size_t)h * SS_ * DD_, DD_, DKK_,
                          my * 64, nx * 64);
        }
    }
    grid.sync();

    // ================= P3: scores (288 items = 8h x 6my x 6nx) =============
    part(288, nb, bid, lo, hi);
    for (int it = lo; it < hi; ++it) {
        const int h = it / 36, rest = it % 36;
        const int my = rest / 6, nx = rest % 6;
        tile64<true>(As, Bs,
                     N + (size_t)h * SS_ * DKK_, DKK_,
                     k + h * DKK_, DD_,
                     nullptr, r + h * SS_, z + h * SS_, 0.125f,
                     attn + (size_t)h * SSZ_, SS_, DKK_,
                     my * 64, nx * 64);
    }
    grid.sync();

    // ================= P4: softmax, one wave per row (3072 rows) ===========
    {
        const int nwaves = nb * 4;
        const int lane = tid & 63;
        for (int row = bid * 4 + (tid >> 6); row < HH_ * SS_; row += nwaves) {
            float* p = attn + (size_t)row * SS_;
            float vv[6];
            float m = -INFINITY;
#pragma unroll
            for (int j = 0; j < 6; ++j) {
                vv[j] = p[lane + 64 * j];
                m = fmaxf(m, vv[j]);
            }
#pragma unroll
            for (int st = 1; st < 64; st <<= 1) m = fmaxf(m, __shfl_xor(m, st));
            float ssum = 0.f;
#pragma unroll
            for (int j = 0; j < 6; ++j) { vv[j] = __expf(vv[j] - m); ssum += vv[j]; }
#pragma unroll
            for (int st = 1; st < 64; st <<= 1) ssum += __shfl_xor(ssum, st);
            const float inv = 1.0f / ssum;
            const int row7 = row - 7 * SS_;
#pragma unroll
            for (int j = 0; j < 6; ++j) {
                const float val = vv[j] * inv;
                p[lane + 64 * j] = val;
                if (row7 >= 0) out1[(size_t)row7 * SS_ + lane + 64 * j] = val;
            }
        }
    }
    grid.sync();

    // ================= P5: epilogue (4608 items = 384t x 12sy) =============
    // out[s,t,:] = sum_h attn[h,s,t]*hvo[h,t,:] + bo
    {
        float* aT = &As[0][0];                     // reuse LDS, 256 floats
        const int dq = (tid & 127) << 2;           // 0..508 step 4
        const int sh = tid >> 7;                   // si parity
        const f32x4 b4 = *(const f32x4*)(bo + dq);
        part(4608, nb, bid, lo, hi);
        for (int e = lo; e < hi; ++e) {
            const int t = e / 12, s0 = (e % 12) * 32;
            __syncthreads();                       // aT safe vs prev item
            {
                const int h = tid >> 5, si = tid & 31;
                aT[h * 32 + si] =
                    attn[(size_t)h * SSZ_ + (size_t)(s0 + si) * SS_ + t];
            }
            __syncthreads();
            f32x4 hv[HH_];
#pragma unroll
            for (int h = 0; h < HH_; ++h)
                hv[h] = *(const f32x4*)(hvo + ((size_t)h * SS_ + t) * DD_ + dq);
#pragma unroll
            for (int i = 0; i < 16; ++i) {
                const int si = sh + (i << 1);
                f32x4 o = b4;
#pragma unroll
                for (int h = 0; h < HH_; ++h) {
                    const float a = aT[h * 32 + si];
                    o.x = fmaf(a, hv[h].x, o.x);
                    o.y = fmaf(a, hv[h].y, o.y);
                    o.z = fmaf(a, hv[h].z, o.z);
                    o.w = fmaf(a, hv[h].w, o.w);
                }
                float* pp = out0 + ((size_t)(s0 + si) * SS_ + t) * DD_ + dq;
                __builtin_nontemporal_store(o, (f32x4*)pp);
            }
        }
    }
}

extern "C" void kernel_launch(void* const* d_in, const int* in_sizes, int n_in,
                              void* d_out, int out_size, void* d_ws, size_t ws_size,
                              hipStream_t stream) {
    const float* x    = (const float*)d_in[0];
    const float* Wq   = (const float*)d_in[1];
    const float* bq   = (const float*)d_in[2];
    const float* Wk   = (const float*)d_in[3];
    const float* bk   = (const float*)d_in[4];
    const float* Wv   = (const float*)d_in[5];
    const float* bv   = (const float*)d_in[6];
    const float* Wq_h = (const float*)d_in[7];
    const float* bq_h = (const float*)d_in[8];
    const float* Wk_h = (const float*)d_in[9];
    const float* bk_h = (const float*)d_in[10];
    const float* Wv_s = (const float*)d_in[11];
    const float* bv_s = (const float*)d_in[12];
    const float* Wo   = (const float*)d_in[13];
    const float* bo   = (const float*)d_in[14];

    const size_t SD  = (size_t)SS_ * DD_;    // 196608
    float* ws = (float*)d_ws;
    float* q    = ws;               ws += SD;
    float* k    = ws;               ws += SD;
    float* v    = ws;               ws += SD;
    float* M    = ws;               ws += (size_t)HH_ * DKK_ * DKK_;  // 32768
    float* uq   = ws;               ws += HH_ * DKK_;                 // 512
    float* uk   = ws;               ws += HH_ * DKK_;                 // 512
    float* cc   = ws;               ws += 32;                         // 8 (padded)
    float* N    = ws;               ws += (size_t)HH_ * SS_ * DKK_;   // 196608
    float* r    = ws;               ws += HH_ * SS_;                  // 3072
    float* z    = ws;               ws += HH_ * SS_;                  // 3072
    float* P    = ws;               ws += (size_t)DKK_ * DD_;         // 32768
    float* pb   = ws;               ws += DD_;                        // 512
    float* attn = ws;               ws += (size_t)HH_ * SSZ_;         // 1179648
    float* hvo  = ws;               ws += (size_t)HH_ * SD;           // 1572864

    float* out0 = (float*)d_out;                   // [1,384,384,512] fp32
    float* out1 = out0 + (size_t)SS_ * SS_ * DD_;  // [1,384,384] fp32

    // grid: co-resident cooperative launch. LDS 33.3 KB/block => >=3 blocks/CU
    // by arithmetic; clamp via occupancy query (cached) for safety.
    static int nb_cached = 0;
    if (nb_cached == 0) {
        int perCU = 0;
        if (hipOccupancyMaxActiveBlocksPerMultiprocessor(
                &perCU, (const void*)mega_kernel, 256, 0) != hipSuccess || perCU < 1)
            perCU = 3;
        int nb = perCU * 256;
        if (nb > 768) nb = 768;      // 768 = exact fit: 3072 softmax rows / 4 waves
        nb_cached = nb;
    }

    void* args[] = {
        (void*)&x, (void*)&Wq, (void*)&bq, (void*)&Wk, (void*)&bk,
        (void*)&Wv, (void*)&bv, (void*)&Wq_h, (void*)&bq_h, (void*)&Wk_h,
        (void*)&bk_h, (void*)&Wv_s, (void*)&bv_s, (void*)&Wo, (void*)&bo,
        (void*)&q, (void*)&k, (void*)&v, (void*)&M, (void*)&uq, (void*)&uk,
        (void*)&cc, (void*)&N, (void*)&r, (void*)&z, (void*)&P, (void*)&pb,
        (void*)&attn, (void*)&hvo, (void*)&out0, (void*)&out1
    };
    hipLaunchCooperativeKernel((const void*)mega_kernel, dim3(nb_cached),
                               dim3(256), args, 0, stream);
}

// Round 3
// 462.733 us; speedup vs baseline: 1.2091x; 1.2091x over previous
//
#include <hip/hip_runtime.h>

// InterpretableMultiHeadAttention  B=1, S=384, D=512, H=8, DK=64
// fp32 in/out (R1/R3 findings from prior session).
//
// Factored algebra (exact):
//   scores_h = 0.125*(q_h (Wq_h Wk_h^T) k_h^T + q_h.uq + k_h.uk + c)
//   hvo_h    = v_h (Wv_s Wo / 8) + pb
//   out[s,t,:] = sum_h attn[h,s,t]*hvo[h,t,:] + bo
//
// R4: 12 -> 5 dispatches (-132 us: ~19 us/launch gap).
// R5: coop mega-kernel REGRESSED (497 us kernel; grid.sync ~50 us each;
//     counters: VALU 4.7%, HBM 9% -> latency/stall-bound, writes ~1 TB/s).
// R6 (this round): back to plain launches, 4 dispatches.
//   - Epilogue rewritten store-linear: block = 32s x 4t x 512d, hv in regs,
//     attn tile in LDS loaded once, NO barrier in store loop; each s writes
//     one contiguous 8 KB run (vs 1-2 KB runs at 786 KB stride before).
//   - scores+softmax fused (slab-in-registers, 8-lane shfl softmax), saving
//     a dispatch and the pre-softmax attn write+read.

#define SS_ 384
#define DD_ 512
#define HH_ 8
#define DKK_ 64
#define SSZ_ (SS_ * SS_)

typedef float f32x4 __attribute__((ext_vector_type(4)));

// ---- generic 64x64-tile fp32 GEMM, K multiple of 64, 256 threads ----------
// C[m0+m, n0+n] = scale*(sum_k A[m,k]*B[k,n] + rvec[m] + zvec[n]) + bias[n]
// NT=true: B accessed as B[n, k] (row-major [N,K]).
template <bool NT>
__device__ __forceinline__ void tile64(
    float (* __restrict__ As)[65], float (* __restrict__ Bs)[65],
    const float* __restrict__ A, int lda,
    const float* __restrict__ B, int ldb,
    const float* __restrict__ bias,
    const float* __restrict__ rvec,
    const float* __restrict__ zvec,
    float scale,
    float* __restrict__ C, int ldc, int K, int m0, int n0)
{
    const int tid = threadIdx.x;
    const int lr = tid >> 2;           // 0..63
    const int lc = (tid & 3) << 4;     // 0,16,32,48
    const int ty = tid >> 4, tx = tid & 15;
    float acc[4][4] = {};

    for (int k0 = 0; k0 < K; k0 += 64) {
        const float* Ap = A + (size_t)(m0 + lr) * lda + (k0 + lc);
#pragma unroll
        for (int u = 0; u < 16; u += 4) {
            float4 t4 = *(const float4*)(Ap + u);
            As[lr][lc + u + 0] = t4.x; As[lr][lc + u + 1] = t4.y;
            As[lr][lc + u + 2] = t4.z; As[lr][lc + u + 3] = t4.w;
        }
        if (!NT) {
            const float* Bp = B + (size_t)(k0 + lr) * ldb + (n0 + lc);
#pragma unroll
            for (int u = 0; u < 16; u += 4) {
                float4 t4 = *(const float4*)(Bp + u);
                Bs[lr][lc + u + 0] = t4.x; Bs[lr][lc + u + 1] = t4.y;
                Bs[lr][lc + u + 2] = t4.z; Bs[lr][lc + u + 3] = t4.w;
            }
        } else {
            const float* Bp = B + (size_t)(n0 + lr) * ldb + (k0 + lc);
#pragma unroll
            for (int u = 0; u < 16; ++u) Bs[lc + u][lr] = Bp[u];
        }
        __syncthreads();
#pragma unroll 16
        for (int kk = 0; kk < 64; ++kk) {
            float a[4], b[4];
#pragma unroll
            for (int i = 0; i < 4; ++i) a[i] = As[(ty << 2) + i][kk];
#pragma unroll
            for (int j = 0; j < 4; ++j) b[j] = Bs[kk][(tx << 2) + j];
#pragma unroll
            for (int i = 0; i < 4; ++i)
#pragma unroll
                for (int j = 0; j < 4; ++j)
                    acc[i][j] = fmaf(a[i], b[j], acc[i][j]);
        }
        __syncthreads();
    }
#pragma unroll
    for (int i = 0; i < 4; ++i) {
        const int m = m0 + (ty << 2) + i;
#pragma unroll
        for (int j = 0; j < 4; ++j) {
            const int n = n0 + (tx << 2) + j;
            float val = acc[i][j];
            if (rvec) val += rvec[m];
            if (zvec) val += zvec[n];
            val *= scale;
            if (bias) val += bias[n];
            C[(size_t)m * ldc + n] = val;
        }
    }
}

// ---- stage1: all input-only work (167 blocks) ------------------------------
// 0..7 pcM | 8..12 pcUV | 13..20 pcP | 21..22 pcPb | 23..166 qkv
__global__ __launch_bounds__(256) void stage1_kernel(
    const float* __restrict__ x,
    const float* __restrict__ Wq, const float* __restrict__ bq,
    const float* __restrict__ Wk, const float* __restrict__ bk,
    const float* __restrict__ Wv, const float* __restrict__ bv,
    const float* __restrict__ Wq_h, const float* __restrict__ bq_h,
    const float* __restrict__ Wk_h, const float* __restrict__ bk_h,
    const float* __restrict__ Wv_s, const float* __restrict__ bv_s,
    const float* __restrict__ Wo,
    float* __restrict__ q, float* __restrict__ k, float* __restrict__ v,
    float* __restrict__ M, float* __restrict__ uq, float* __restrict__ uk,
    float* __restrict__ cc, float* __restrict__ P, float* __restrict__ pb)
{
    __shared__ float As[64][65];
    __shared__ float Bs[64][65];
    const int b = blockIdx.x;
    const int tid = threadIdx.x;
    if (b < 8) {
        const int h = b;
        tile64<true>(As, Bs,
                     Wq_h + (size_t)h * DKK_ * DD_, DD_,
                     Wk_h + (size_t)h * DKK_ * DD_, DD_,
                     nullptr, nullptr, nullptr, 1.0f,
                     M + (size_t)h * DKK_ * DKK_, DKK_, DD_, 0, 0);
    } else if (b < 13) {
        const int id = (b - 8) * 256 + tid;
        if (id < 512) {
            const int h = id >> 6, i = id & 63;
            float s = 0.f;
            for (int d = 0; d < DD_; ++d)
                s = fmaf(Wq_h[(size_t)(h * DKK_ + i) * DD_ + d], bk_h[h * DD_ + d], s);
            uq[id] = s;
        } else if (id < 1024) {
            const int t2 = id - 512, h = t2 >> 6, j = t2 & 63;
            float s = 0.f;
            for (int d = 0; d < DD_; ++d)
                s = fmaf(Wk_h[(size_t)(h * DKK_ + j) * DD_ + d], bq_h[h * DD_ + d], s);
            uk[t2] = s;
        } else if (id < 1032) {
            const int h = id - 1024;
            float s = 0.f;
            for (int d = 0; d < DD_; ++d)
                s = fmaf(bq_h[h * DD_ + d], bk_h[h * DD_ + d], s);
            cc[h] = s;
        }
    } else if (b < 21) {
        tile64<false>(As, Bs, Wv_s, DD_, Wo, DD_, nullptr, nullptr, nullptr,
                      0.125f, P, DD_, DD_, 0, (b - 13) * 64);
    } else if (b < 23) {
        const int e = (b - 21) * 256 + tid;
        if (e < DD_) {
            float s = 0.f;
            for (int d = 0; d < DD_; ++d)
                s = fmaf(bv_s[d], Wo[(size_t)d * DD_ + e], s);
            pb[e] = 0.125f * s;
        }
    } else {
        const int id = b - 23;                 // 0..143
        const int zi = id / 48;
        const int rem = id % 48;
        const int my = rem >> 3, nx = rem & 7;
        const float *W, *bias; float* C;
        if (zi == 0)      { W = Wq; bias = bq; C = q; }
        else if (zi == 1) { W = Wk; bias = bk; C = k; }
        else              { W = Wv; bias = bv; C = v; }
        tile64<false>(As, Bs, x, DD_, W, DD_, bias, nullptr, nullptr, 1.0f,
                      C, DD_, DD_, my * 64, nx * 64);
    }
}

// ---- stage2: N / r,z / hvo (456 blocks) ------------------------------------
__global__ __launch_bounds__(256) void stage2_kernel(
    const float* __restrict__ q, const float* __restrict__ k,
    const float* __restrict__ v,
    const float* __restrict__ M, const float* __restrict__ uq,
    const float* __restrict__ uk, const float* __restrict__ cc,
    const float* __restrict__ P, const float* __restrict__ pb,
    float* __restrict__ N, float* __restrict__ r, float* __restrict__ z,
    float* __restrict__ hvo)
{
    __shared__ float As[64][65];
    __shared__ float Bs[64][65];
    const int b = blockIdx.x;
    const int tid = threadIdx.x;
    if (b < 48) {
        const int h = b / 6, mx = b % 6;
        tile64<false>(As, Bs, q + h * DKK_, DD_,
                      M + (size_t)h * DKK_ * DKK_, DKK_,
                      nullptr, nullptr, nullptr, 1.0f,
                      N + (size_t)h * SS_ * DKK_, DKK_, DKK_, mx * 64, 0);
    } else if (b < 72) {
        const int id = (b - 48) * 256 + tid;
        if (id < HH_ * SS_) {
            const int h = id / SS_, s = id % SS_;
            float acc = cc[h];
            for (int i = 0; i < DKK_; ++i)
                acc = fmaf(q[(size_t)s * DD_ + h * DKK_ + i], uq[h * DKK_ + i], acc);
            r[id] = acc;
        } else if (id < 2 * HH_ * SS_) {
            const int t2 = id - HH_ * SS_;
            const int h = t2 / SS_, t = t2 % SS_;
            float acc = 0.f;
            for (int j = 0; j < DKK_; ++j)
                acc = fmaf(k[(size_t)t * DD_ + h * DKK_ + j], uk[h * DKK_ + j], acc);
            z[t2] = acc;
        }
    } else {
        const int id = b - 72;                 // 0..383
        const int nx = id & 7;
        const int my = (id >> 3) % 6;
        const int h = id / 48;
        tile64<false>(As, Bs, v + h * DKK_, DD_, P, DD_, pb, nullptr, nullptr,
                      1.0f, hvo + (size_t)h * SS_ * DD_, DD_, DKK_,
                      my * 64, nx * 64);
    }
}

// ---- fused scores+softmax (96 blocks = 8h x 12 s-tiles of 32) --------------
// Block computes full 32x384 score slab in registers, softmaxes rows via
// 8-lane shfl groups, writes post-softmax attn (+ out1 for h==7).
__global__ __launch_bounds__(256) void scoresmax_kernel(
    const float* __restrict__ N, const float* __restrict__ k,
    const float* __restrict__ r, const float* __restrict__ z,
    float* __restrict__ attn, float* __restrict__ out1)
{
    __shared__ float Nt[32][68];
    __shared__ float kt[64][68];
    const int bid = blockIdx.x;
    const int h = bid & 7, mtile = bid >> 3;   // bid%8==h -> same-h blocks spread XCDs
    const int s0 = mtile * 32;
    const int tid = threadIdx.x;
    const int s_loc = tid >> 3, tc = tid & 7;  // row owner: 8 consecutive lanes/row

    {   // stage Nt (32 x 64), float4 loads, aligned LDS rows (pad 68)
        const int sl = tid >> 3, kc = (tid & 7) * 8;
        const float* src = N + ((size_t)h * SS_ + s0 + sl) * DKK_ + kc;
        *(f32x4*)&Nt[sl][kc]     = *(const f32x4*)src;
        *(f32x4*)&Nt[sl][kc + 4] = *(const f32x4*)(src + 4);
    }
    const float rs = r[h * SS_ + s0 + s_loc];

    float acc[6][8];
#pragma unroll
    for (int a = 0; a < 6; ++a)
#pragma unroll
        for (int u = 0; u < 8; ++u) acc[a][u] = 0.f;

    const int lr = tid >> 2, lc = (tid & 3) << 4;
#pragma unroll
    for (int tt = 0; tt < 6; ++tt) {           // full unroll: acc statically indexed
        __syncthreads();
        {   // stage kt transposed: kt[kk][t_loc]  (k rows t0..t0+63, feats h*64..)
            const float* kp = k + (size_t)(tt * 64 + lr) * DD_ + h * DKK_ + lc;
#pragma unroll
            for (int u = 0; u < 16; ++u) kt[lc + u][lr] = kp[u];
        }
        __syncthreads();
#pragma unroll 8
        for (int kk = 0; kk < 64; ++kk) {
            const float a = Nt[s_loc][kk];
            const f32x4 b0 = *(const f32x4*)&kt[kk][tc * 8];
            const f32x4 b1 = *(const f32x4*)&kt[kk][tc * 8 + 4];
            acc[tt][0] = fmaf(a, b0.x, acc[tt][0]);
            acc[tt][1] = fmaf(a, b0.y, acc[tt][1]);
            acc[tt][2] = fmaf(a, b0.z, acc[tt][2]);
            acc[tt][3] = fmaf(a, b0.w, acc[tt][3]);
            acc[tt][4] = fmaf(a, b1.x, acc[tt][4]);
            acc[tt][5] = fmaf(a, b1.y, acc[tt][5]);
            acc[tt][6] = fmaf(a, b1.z, acc[tt][6]);
            acc[tt][7] = fmaf(a, b1.w, acc[tt][7]);
        }
    }

    // finalize scores = 0.125*(acc + rs + z[t]); row max over 48 local + 8 lanes
    float m = -INFINITY;
#pragma unroll
    for (int tt = 0; tt < 6; ++tt) {
        const float* zp = z + h * SS_ + tt * 64 + tc * 8;
        const f32x4 z0 = *(const f32x4*)zp;
        const f32x4 z1 = *(const f32x4*)(zp + 4);
        const float zz[8] = {z0.x, z0.y, z0.z, z0.w, z1.x, z1.y, z1.z, z1.w};
#pragma unroll
        for (int u = 0; u < 8; ++u) {
            const float sc = 0.125f * (acc[tt][u] + rs + zz[u]);
            acc[tt][u] = sc;
            m = fmaxf(m, sc);
        }
    }
    m = fmaxf(m, __shfl_xor(m, 1));
    m = fmaxf(m, __shfl_xor(m, 2));
    m = fmaxf(m, __shfl_xor(m, 4));
    float ssum = 0.f;
#pragma unroll
    for (int tt = 0; tt < 6; ++tt)
#pragma unroll
        for (int u = 0; u < 8; ++u) {
            acc[tt][u] = __expf(acc[tt][u] - m);
            ssum += acc[tt][u];
        }
    ssum += __shfl_xor(ssum, 1);
    ssum += __shfl_xor(ssum, 2);
    ssum += __shfl_xor(ssum, 4);
    const float inv = 1.0f / ssum;

    float* arow = attn + (size_t)h * SSZ_ + (size_t)(s0 + s_loc) * SS_ + tc * 8;
    float* orow = out1 + (size_t)(s0 + s_loc) * SS_ + tc * 8;
#pragma unroll
    for (int tt = 0; tt < 6; ++tt) {
        f32x4 v0, v1;
        v0.x = acc[tt][0] * inv; v0.y = acc[tt][1] * inv;
        v0.z = acc[tt][2] * inv; v0.w = acc[tt][3] * inv;
        v1.x = acc[tt][4] * inv; v1.y = acc[tt][5] * inv;
        v1.z = acc[tt][6] * inv; v1.w = acc[tt][7] * inv;
        *(f32x4*)(arow + tt * 64)     = v0;
        *(f32x4*)(arow + tt * 64 + 4) = v1;
        if (h == 7) {
            *(f32x4*)(orow + tt * 64)     = v0;
            *(f32x4*)(orow + tt * 64 + 4) = v1;
        }
    }
}

// ---- epilogue: store-linear (1152 blocks = 12 sg x 96 tg) ------------------
// Block = 32 s x 4 t x 512 d. hv in registers (fixed (t,d) per thread across
// the s-loop), attn tile gathered once into 4KB LDS, NO barrier in s-loop.
// Each s-step stores one contiguous 8 KB run (4 adjacent t-rows).
__global__ __launch_bounds__(256) void epilogue_kernel(
    const float* __restrict__ attn, const float* __restrict__ hvo,
    const float* __restrict__ bo, float* __restrict__ out)
{
    __shared__ float aT[HH_][4][32];           // 4 KB
    const int bid = blockIdx.x;
    const int sg = bid / 96, tg = bid % 96;    // same-tg blocks: bid diff 96 (%8==0)
    const int s0 = sg * 32, t0 = tg * 4;       //   -> same XCD -> hvo L2 reuse
    const int tid = threadIdx.x;
    const int tl = tid >> 6;                   // wave id = t offset 0..3
    const int dq = (tid & 63) * 8;             // 32 B per lane

#pragma unroll
    for (int i = 0; i < 4; ++i) {              // gather 8h x 4t x 32s attn tile
        const int idx = tid + i * 256;
        const int hh = idx >> 7, tli = (idx >> 5) & 3, sl = idx & 31;
        aT[hh][tli][sl] =
            attn[(size_t)hh * SSZ_ + (size_t)(s0 + sl) * SS_ + t0 + tli];
    }
    f32x4 hva[HH_], hvb[HH_];
#pragma unroll
    for (int h = 0; h < HH_; ++h) {
        const float* hp = hvo + ((size_t)h * SS_ + t0 + tl) * DD_ + dq;
        hva[h] = *(const f32x4*)hp;
        hvb[h] = *(const f32x4*)(hp + 4);
    }
    const f32x4 b4a = *(const f32x4*)(bo + dq);
    const f32x4 b4b = *(const f32x4*)(bo + dq + 4);
    __syncthreads();                           // the ONLY barrier

    for (int s = 0; s < 32; ++s) {
        f32x4 oa = b4a, ob = b4b;
#pragma unroll
        for (int h = 0; h < HH_; ++h) {
            const float a = aT[h][tl][s];      // wave-uniform -> broadcast
            oa.x = fmaf(a, hva[h].x, oa.x);
            oa.y = fmaf(a, hva[h].y, oa.y);
            oa.z = fmaf(a, hva[h].z, oa.z);
            oa.w = fmaf(a, hva[h].w, oa.w);
            ob.x = fmaf(a, hvb[h].x, ob.x);
            ob.y = fmaf(a, hvb[h].y, ob.y);
            ob.z = fmaf(a, hvb[h].z, ob.z);
            ob.w = fmaf(a, hvb[h].w, ob.w);
        }
        float* p = out + ((size_t)(s0 + s) * SS_ + t0 + tl) * DD_ + dq;
        __builtin_nontemporal_store(oa, (f32x4*)p);
        __builtin_nontemporal_store(ob, (f32x4*)(p + 4));
    }
}

extern "C" void kernel_launch(void* const* d_in, const int* in_sizes, int n_in,
                              void* d_out, int out_size, void* d_ws, size_t ws_size,
                              hipStream_t stream) {
    const float* x    = (const float*)d_in[0];
    const float* Wq   = (const float*)d_in[1];
    const float* bq   = (const float*)d_in[2];
    const float* Wk   = (const float*)d_in[3];
    const float* bk   = (const float*)d_in[4];
    const float* Wv   = (const float*)d_in[5];
    const float* bv   = (const float*)d_in[6];
    const float* Wq_h = (const float*)d_in[7];
    const float* bq_h = (const float*)d_in[8];
    const float* Wk_h = (const float*)d_in[9];
    const float* bk_h = (const float*)d_in[10];
    const float* Wv_s = (const float*)d_in[11];
    const float* bv_s = (const float*)d_in[12];
    const float* Wo   = (const float*)d_in[13];
    const float* bo   = (const float*)d_in[14];

    const size_t SD  = (size_t)SS_ * DD_;    // 196608
    float* ws = (float*)d_ws;
    float* q    = ws;               ws += SD;
    float* k    = ws;               ws += SD;
    float* v    = ws;               ws += SD;
    float* M    = ws;               ws += (size_t)HH_ * DKK_ * DKK_;  // 32768
    float* uq   = ws;               ws += HH_ * DKK_;                 // 512
    float* uk   = ws;               ws += HH_ * DKK_;                 // 512
    float* cc   = ws;               ws += 32;                         // 8 (padded)
    float* N    = ws;               ws += (size_t)HH_ * SS_ * DKK_;   // 196608
    float* r    = ws;               ws += HH_ * SS_;                  // 3072
    float* z    = ws;               ws += HH_ * SS_;                  // 3072
    float* P    = ws;               ws += (size_t)DKK_ * DD_;         // 32768
    float* pb   = ws;               ws += DD_;                        // 512
    float* attn = ws;               ws += (size_t)HH_ * SSZ_;         // 1179648
    float* hvo  = ws;               ws += (size_t)HH_ * SD;           // 1572864

    float* out0 = (float*)d_out;                   // [1,384,384,512] fp32
    float* out1 = out0 + (size_t)SS_ * SS_ * DD_;  // [1,384,384] fp32

    stage1_kernel  <<<dim3(167),  256, 0, stream>>>(
        x, Wq, bq, Wk, bk, Wv, bv, Wq_h, bq_h, Wk_h, bk_h, Wv_s, bv_s, Wo,
        q, k, v, M, uq, uk, cc, P, pb);
    stage2_kernel  <<<dim3(456),  256, 0, stream>>>(
        q, k, v, M, uq, uk, cc, P, pb, N, r, z, hvo);
    scoresmax_kernel<<<dim3(96),  256, 0, stream>>>(N, k, r, z, attn, out1);
    epilogue_kernel<<<dim3(1152), 256, 0, stream>>>(attn, hvo, bo, out0);
}